// Round 2
// baseline (210.573 us; speedup 1.0000x reference)
//
#include <hip/hip_runtime.h>
#include <hip/hip_fp16.h>

// GCNConv (PyG semantics) + eval-dropout(identity) + ReLU, fp32 in/out.
// N=100000 nodes, E=1600000 edges, D=64.
//
//  1. k_part: single-pass bucket partition. LDS hist -> scan -> LDS sort ->
//     COALESCED run writes of packed=(row<<7)|(col&127). Also: global
//     deg[col]++ atomics (replaces old k_dis), block 0 builds transposed
//     bf16 W (WT[n][k]) and zeroes dummy row N of xw_h.
//  2. k_gemm: xw_h[r] = fp16((x@W)[r] * rsqrt(deg[r]+1)) via
//     mfma_f32_16x16x32_bf16 with SWAPPED operands (C comes out transposed
//     per-tile -> each thread holds 4 consecutive cols of one row -> 8B
//     stores). B-frags are direct 16B loads from WT. 2 tiles/wave, no LDS.
//  3. k_gather: per bucket (BW=128, 512 thr): LDS hist+scan+sort with node
//     segments PADDED to x4 using dummy row N (zeros). Gather is
//     per-lane-node: lane=(node 0..3, chunk 0..15), each lane serially
//     accumulates its node's edges 4-unrolled (4 loads in flight, no
//     cross-lane reduce, no serial remainder). Fused bias+ReLU.
//
// Workspace: 22.84 MB (kept under the previously-passing 22.86 MB footprint;
// round-1 attempt exceeded it and died in-container).

#define D 64
#define BW 128            // dest nodes per bucket
#define CAP 3072          // per-bucket edge capacity (mean 2048, +22 sigma)
#define CAPP 3456         // CAP + 3*BW (padded LDS size)
#define EPT 16            // edges per thread in k_part
#define PART_T 256
#define EPB (PART_T * EPT) // 4096 edges per k_part block
#define NBMAX 1024

typedef __attribute__((ext_vector_type(8))) short bf16x8;
typedef __attribute__((ext_vector_type(4))) float f32x4;

__device__ __forceinline__ unsigned short f2bf(float f) {   // RNE fp32->bf16
    unsigned u = __float_as_uint(f);
    u += 0x7FFFu + ((u >> 16) & 1u);
    return (unsigned short)(u >> 16);
}

// ---- 1. partition: hist -> scan -> LDS sort -> coalesced write -------------
__global__ __launch_bounds__(256)
void k_part(const int* __restrict__ row, const int* __restrict__ col,
            int* __restrict__ gcur, int* __restrict__ packed,
            int* __restrict__ deg, unsigned short* __restrict__ WT,
            const float* __restrict__ W, unsigned short* __restrict__ xw_h,
            int E, int NBUCK, int N) {
    __shared__ int lh[NBMAX], base[NBMAX], lst[NBMAX];
    __shared__ int wsc[4];
    __shared__ int srtv[EPB], srta[EPB];
    int tid = threadIdx.x;
    for (int i = tid; i < NBUCK; i += PART_T) lh[i] = 0;
    __syncthreads();
    int e0 = blockIdx.x * EPB + tid;
    int rr[EPT], cc[EPT], pp[EPT];
#pragma unroll
    for (int i = 0; i < EPT; ++i) {
        int e = e0 + i * PART_T;
        if (e < E) {
            cc[i] = col[e];
            rr[i] = row[e];
            pp[i] = atomicAdd(&lh[cc[i] >> 7], 1);   // local rank in bucket
            atomicAdd(&deg[cc[i]], 1);               // global in-degree
        } else {
            cc[i] = -1;
        }
    }
    __syncthreads();
    // global base per bucket (rotated to spread atomic contention)
    int rot = (int)((blockIdx.x * 97u) % (unsigned)NBUCK);
    for (int j = tid; j < NBUCK; j += PART_T) {
        int bu = j + rot; if (bu >= NBUCK) bu -= NBUCK;
        int h = lh[bu];
        if (h > 0) base[bu] = atomicAdd(&gcur[bu * 8], h);
    }
    // local exclusive scan over NBUCK counts, 4 entries/thread
    int lane = tid & 63, wv = tid >> 6;
    int i0 = tid * 4;
    int v0 = (i0     < NBUCK) ? lh[i0]     : 0;
    int v1 = (i0 + 1 < NBUCK) ? lh[i0 + 1] : 0;
    int v2 = (i0 + 2 < NBUCK) ? lh[i0 + 2] : 0;
    int v3 = (i0 + 3 < NBUCK) ? lh[i0 + 3] : 0;
    int s4 = v0 + v1 + v2 + v3, inc = s4;
#pragma unroll
    for (int off = 1; off < 64; off <<= 1) {
        int u = __shfl_up(inc, off);
        if (lane >= off) inc += u;
    }
    if (lane == 63) wsc[wv] = inc;
    __syncthreads();
    int woff = 0;
#pragma unroll
    for (int w = 0; w < 4; ++w) woff += (w < wv) ? wsc[w] : 0;
    int ex = woff + inc - s4;
    if (i0     < NBUCK) lst[i0]     = ex;
    if (i0 + 1 < NBUCK) lst[i0 + 1] = ex + v0;
    if (i0 + 2 < NBUCK) lst[i0 + 2] = ex + v0 + v1;
    if (i0 + 3 < NBUCK) lst[i0 + 3] = ex + v0 + v1 + v2;
    __syncthreads();
    // scatter (value, global addr) into LDS sorted by bucket
#pragma unroll
    for (int i = 0; i < EPT; ++i) {
        if (cc[i] >= 0) {
            int bu = cc[i] >> 7;
            int p = lst[bu] + pp[i];
            srtv[p] = (rr[i] << 7) | (cc[i] & 127);
            int g = base[bu] + pp[i];
            srta[p] = (g < CAP) ? bu * CAP + g : -1;
        }
    }
    __syncthreads();
    int tot = min(EPB, E - blockIdx.x * EPB);
    for (int p = tid; p < tot; p += PART_T) {      // coalesced run writes
        int a = srta[p];
        if (a >= 0) packed[a] = srtv[p];
    }
    // block 0 extras: transposed bf16 W, zero dummy row N
    if (blockIdx.x == 0) {
        for (int i = tid; i < 4096; i += PART_T) {
            int n = i >> 6, k = i & 63;
            WT[i] = f2bf(W[k * 64 + n]);           // WT[n][k]
        }
        if (tid < 32) ((unsigned*)xw_h)[(size_t)N * 32 + tid] = 0u;
    }
}

// ---- 2. MFMA GEMM (transposed-C) + rsqrt(deg+1) pre-scale -> fp16 ----------
// mfma(A=W^T-frag, B=x-frag): D[i][j] = xw[row0+j][t*16+i]; thread (m,quad)
// holds row row0+m, cols t*16+quad*4+r (r=0..3) -> 8B stores.
__global__ __launch_bounds__(256, 4)
void k_gemm(const float* __restrict__ x, const unsigned short* __restrict__ WT,
            const int* __restrict__ deg, unsigned short* __restrict__ xw_h,
            int N, int NT, int TOTW) {
    int tid = threadIdx.x, lane = tid & 63, wv = tid >> 6;
    int m = lane & 15, quad = lane >> 4;
    bf16x8 Bf[4][2];
#pragma unroll
    for (int t = 0; t < 4; ++t)
#pragma unroll
        for (int s = 0; s < 2; ++s)
            Bf[t][s] = *(const bf16x8*)(WT + (t * 16 + m) * 64 + s * 32 + quad * 8);
    int wid = blockIdx.x * 4 + wv;
    for (int mt = wid; mt < NT; mt += TOTW) {
        int row0 = mt * 16;
        const float* xr = x + (size_t)(row0 + m) * 64 + quad * 8;
        float4 a0 = *(const float4*)(xr);
        float4 a1 = *(const float4*)(xr + 4);
        float4 a2 = *(const float4*)(xr + 32);
        float4 a3 = *(const float4*)(xr + 36);
        bf16x8 A0, A1;
        A0[0] = (short)f2bf(a0.x); A0[1] = (short)f2bf(a0.y);
        A0[2] = (short)f2bf(a0.z); A0[3] = (short)f2bf(a0.w);
        A0[4] = (short)f2bf(a1.x); A0[5] = (short)f2bf(a1.y);
        A0[6] = (short)f2bf(a1.z); A0[7] = (short)f2bf(a1.w);
        A1[0] = (short)f2bf(a2.x); A1[1] = (short)f2bf(a2.y);
        A1[2] = (short)f2bf(a2.z); A1[3] = (short)f2bf(a2.w);
        A1[4] = (short)f2bf(a3.x); A1[5] = (short)f2bf(a3.y);
        A1[6] = (short)f2bf(a3.z); A1[7] = (short)f2bf(a3.w);
        f32x4 acc[4];
#pragma unroll
        for (int t = 0; t < 4; ++t) {
            acc[t] = (f32x4){0.f, 0.f, 0.f, 0.f};
            acc[t] = __builtin_amdgcn_mfma_f32_16x16x32_bf16(Bf[t][0], A0, acc[t], 0, 0, 0);
            acc[t] = __builtin_amdgcn_mfma_f32_16x16x32_bf16(Bf[t][1], A1, acc[t], 0, 0, 0);
        }
        float dsc = rsqrtf((float)(deg[row0 + m] + 1));
        unsigned short* op = xw_h + (size_t)(row0 + m) * 64 + quad * 4;
#pragma unroll
        for (int t = 0; t < 4; ++t) {
            __half2 h0, h1;
            h0.x = __float2half(acc[t][0] * dsc); h0.y = __float2half(acc[t][1] * dsc);
            h1.x = __float2half(acc[t][2] * dsc); h1.y = __float2half(acc[t][3] * dsc);
            uint2 u; u.x = *(unsigned*)&h0; u.y = *(unsigned*)&h1;
            *(uint2*)(op + t * 16) = u;
        }
    }
}

// ---- 3. fused sort + per-lane-node gather ----------------------------------
__global__ __launch_bounds__(512, 8)
void k_gather(const int* __restrict__ gcur, const int* __restrict__ packed,
              const uint2* __restrict__ xwh, const float* __restrict__ bias,
              float4* __restrict__ out4, int N) {
    __shared__ int lh[BW], stt[BW], cur[BW];
    __shared__ int wsum[2];
    __shared__ __align__(16) int srtL[CAPP];
    int b = blockIdx.x;
    int tid = threadIdx.x;
    if (tid < BW) lh[tid] = 0;
    __syncthreads();
    int sz = min(gcur[b * 8], CAP);
    const int* pk = packed + (size_t)b * CAP;
    for (int i = tid; i < sz; i += 512)
        atomicAdd(&lh[pk[i] & 127], 1);
    __syncthreads();
    int lane = tid & 63;
    // exclusive scan over PADDED (x4) per-node sizes (waves 0-1)
    int v = 0, vp = 0, inc = 0;
    if (tid < BW) {
        v = lh[tid]; vp = (v + 3) & ~3; inc = vp;
#pragma unroll
        for (int off = 1; off < 64; off <<= 1) {
            int u = __shfl_up(inc, off);
            if (lane >= off) inc += u;
        }
        if (lane == 63) wsum[tid >> 6] = inc;
    }
    __syncthreads();
    if (tid < BW) {
        int st = inc - vp + ((tid >> 6) ? wsum[0] : 0);
        stt[tid] = st;
        cur[tid] = st;
    }
    __syncthreads();
    for (int i = tid; i < sz; i += 512) {
        int p = pk[i];
        int pos = atomicAdd(&cur[p & 127], 1);
        srtL[pos] = p >> 7;
    }
    __syncthreads();
    if (tid < BW) {            // pad each segment to x4 with dummy row N
        int e = stt[tid] + v, ep = stt[tid] + vp;
        for (; e < ep; ++e) srtL[e] = N;
    }
    __syncthreads();
    int l = lane & 15;         // dim chunk: dims 4l..4l+3
    int ng = lane >> 4;        // node subgroup 0..3
    int wv = tid >> 6;         // 8 waves
    const float4 bb = ((const float4*)bias)[l];
#define ADDV(h)                                                     \
    {                                                               \
        __half2 h0 = *(__half2*)&(h).x, h1 = *(__half2*)&(h).y;     \
        float2 f0 = __half22float2(h0), f1 = __half22float2(h1);    \
        acc.x += f0.x; acc.y += f0.y; acc.z += f1.x; acc.w += f1.y; \
    }
    for (int g = 0; g < 4; ++g) {
        int nn = wv * 16 + g * 4 + ng;
        int node = b * BW + nn;
        bool active = node < N;
        float4 acc = make_float4(0.f, 0.f, 0.f, 0.f);
        int k = 0, s0 = 0;
        if (active) {
            k = lh[nn]; s0 = stt[nn];
            uint2 hs = xwh[(size_t)node * 16 + l];   // self-loop
            ADDV(hs);
        }
        int kp = (k + 3) & ~3;
        if (kp > 0) {
            int4 rv = *(const int4*)&srtL[s0];
            int j = 0;
            while (true) {
                uint2 va = xwh[(size_t)rv.x * 16 + l];
                uint2 vb = xwh[(size_t)rv.y * 16 + l];
                uint2 vc = xwh[(size_t)rv.z * 16 + l];
                uint2 vd = xwh[(size_t)rv.w * 16 + l];
                j += 4;
                bool more = j < kp;
                if (more) rv = *(const int4*)&srtL[s0 + j];
                ADDV(va); ADDV(vb); ADDV(vc); ADDV(vd);
                if (!more) break;
            }
        }
        if (active) {
            float dn = rsqrtf((float)(k + 1));
            float4 o;
            o.x = fmaxf(fmaf(dn, acc.x, bb.x), 0.f);
            o.y = fmaxf(fmaf(dn, acc.y, bb.y), 0.f);
            o.z = fmaxf(fmaf(dn, acc.z, bb.z), 0.f);
            o.w = fmaxf(fmaf(dn, acc.w, bb.w), 0.f);
            out4[(size_t)node * 16 + l] = o;
        }
    }
#undef ADDV
}

extern "C" void kernel_launch(void* const* d_in, const int* in_sizes, int n_in,
                              void* d_out, int out_size, void* d_ws, size_t ws_size,
                              hipStream_t stream) {
    const float* x    = (const float*)d_in[0];
    const int*   ei   = (const int*)d_in[1];   // int32 (JAX demotes int64)
    const float* W    = (const float*)d_in[2];
    const float* bias = (const float*)d_in[3];
    float* out = (float*)d_out;

    const int N = in_sizes[0] / D;
    const int E = in_sizes[1] / 2;
    const int* row = ei;       // edge_index[0] = sources
    const int* col = ei + E;   // edge_index[1] = destinations

    const int NBUCK = (N + BW - 1) / BW;       // 782
    const int NB1   = (E + EPB - 1) / EPB;     // 391
    const int NT    = (N + 15) / 16;           // 6250 M-tiles
    const int GG    = (NT + 7) / 8;            // 782 gemm blocks (2 tiles/wave)

    char* ws = (char*)d_ws;
    size_t off = 0;
    unsigned short* xw_h = (unsigned short*)(ws + off);
    off += (size_t)(N + 1) * D * sizeof(unsigned short);           // +1 dummy row
    int* packed = (int*)(ws + off); off += (size_t)NBUCK * CAP * sizeof(int);
    int* gcur   = (int*)(ws + off); off += (size_t)NBUCK * 8 * sizeof(int);
    int* deg    = (int*)(ws + off); off += (size_t)N * sizeof(int);
    off = (off + 15) & ~(size_t)15;
    unsigned short* WT = (unsigned short*)(ws + off); off += 4096 * sizeof(unsigned short);

    // zero gcur + deg in one shot (contiguous)
    hipMemsetAsync(gcur, 0, (size_t)NBUCK * 8 * sizeof(int) + (size_t)N * sizeof(int), stream);
    k_part<<<NB1, PART_T, 0, stream>>>(row, col, gcur, packed, deg, WT, W, xw_h, E, NBUCK, N);
    k_gemm<<<GG, 256, 0, stream>>>(x, WT, deg, xw_h, N, NT, GG * 4);
    k_gather<<<NBUCK, 512, 0, stream>>>(gcur, packed, (const uint2*)xw_h, bias,
                                        (float4*)out, N);
}

// Round 3
// 171.863 us; speedup vs baseline: 1.2252x; 1.2252x over previous
//
#include <hip/hip_runtime.h>
#include <hip/hip_fp16.h>

// GCNConv (PyG semantics) + eval-dropout(identity) + ReLU, fp32 in/out.
// N=100000 nodes, E=1600000 edges, D=64.
//
// NO global atomics anywhere (round-2 post-mortem: 1.6M device-scope deg
// atomics + partial-line scatter runs made k_part 81.9us, WRITE_SIZE 72MB).
//
//  1. k_part: per-block LDS bucket-sort of 4096 edges; writes its OWN
//     contiguous 16KB packed region (write amp = 1.0) + per-(block,bucket)
//     offset row (exclusive scan). packed=(row<<7)|(col&127), block-major.
//     Block 0 also builds transposed bf16 W and zeroes dummy row N of xw_h.
//  2. k_gemm: block g == bucket g (8 M-tiles = 128 rows). First builds the
//     bucket in-degree histogram in LDS (segment walk over off-table),
//     writes deg8[node] (1B) for k_gather, then
//     xw_h[r] = fp16((x@W)[r] * rsqrt(deg[r]+1)) via mfma_f32_16x16x32_bf16
//     with swapped operands (transposed-C -> 8B stores), B-frags straight
//     16B loads from WT. No global deg array round-trip for itself.
//  3. k_gather: per bucket (BW=128, 512 thr): lh from deg8 (no hist pass),
//     padded-x4 scan, ONE segment walk to rank-scatter rows into srtL
//     (padded with dummy row N = zeros). Gather is per-lane-node: lane =
//     (node 0..3, chunk 0..15); each lane serially accumulates its node's
//     edges 4-unrolled (4 loads in flight, no cross-lane reduce, no serial
//     remainder). Fused bias+ReLU.
//
// Workspace ~20.6 MB (< 22.84 MB proven-safe footprint).

#define D 64
#define BW 128             // dest nodes per bucket
#define CAPL 3456          // srtL LDS capacity (mean 2048+pad, +~30 sigma)
#define EPT 16             // edges per thread in k_part
#define PART_T 256
#define EPB (PART_T * EPT) // 4096 edges per k_part block
#define NBMAX 1024

typedef __attribute__((ext_vector_type(8))) short bf16x8;
typedef __attribute__((ext_vector_type(4))) float f32x4;

__device__ __forceinline__ unsigned short f2bf(float f) {   // RNE fp32->bf16
    unsigned u = __float_as_uint(f);
    u += 0x7FFFu + ((u >> 16) & 1u);
    return (unsigned short)(u >> 16);
}

// ---- 1. partition: LDS hist -> scan -> LDS sort -> block-major write -------
__global__ __launch_bounds__(256)
void k_part(const int* __restrict__ row, const int* __restrict__ col,
            int* __restrict__ packed, int* __restrict__ off,
            unsigned short* __restrict__ WT, const float* __restrict__ W,
            unsigned short* __restrict__ xw_h,
            int E, int NBUCK, int N) {
    __shared__ int lh[NBMAX];
    __shared__ int lst[NBMAX + 1];
    __shared__ int wsc[4];
    __shared__ int srtv[EPB];
    int tid = threadIdx.x;
    for (int i = tid; i < NBUCK; i += PART_T) lh[i] = 0;
    __syncthreads();
    int e0 = blockIdx.x * EPB + tid;
    int rr[EPT], cc[EPT], pp[EPT];
#pragma unroll
    for (int i = 0; i < EPT; ++i) {
        int e = e0 + i * PART_T;
        if (e < E) {
            cc[i] = col[e];
            rr[i] = row[e];
            pp[i] = atomicAdd(&lh[cc[i] >> 7], 1);   // LDS rank in bucket
        } else {
            cc[i] = -1;
        }
    }
    __syncthreads();
    // exclusive scan over NBUCK counts, 4 entries/thread (covers <=1024)
    int lane = tid & 63, wv = tid >> 6;
    int i0 = tid * 4;
    int v0 = (i0     < NBUCK) ? lh[i0]     : 0;
    int v1 = (i0 + 1 < NBUCK) ? lh[i0 + 1] : 0;
    int v2 = (i0 + 2 < NBUCK) ? lh[i0 + 2] : 0;
    int v3 = (i0 + 3 < NBUCK) ? lh[i0 + 3] : 0;
    int s4 = v0 + v1 + v2 + v3, inc = s4;
#pragma unroll
    for (int o = 1; o < 64; o <<= 1) {
        int u = __shfl_up(inc, o);
        if (lane >= o) inc += u;
    }
    if (lane == 63) wsc[wv] = inc;
    __syncthreads();
    int woff = 0;
#pragma unroll
    for (int w = 0; w < 4; ++w) woff += (w < wv) ? wsc[w] : 0;
    int ex = woff + inc - s4;
    if (i0     < NBUCK) lst[i0]     = ex;
    if (i0 + 1 < NBUCK) lst[i0 + 1] = ex + v0;
    if (i0 + 2 < NBUCK) lst[i0 + 2] = ex + v0 + v1;
    if (i0 + 3 < NBUCK) lst[i0 + 3] = ex + v0 + v1 + v2;
    int tot = min(EPB, E - blockIdx.x * EPB);
    if (tid == 0) lst[NBUCK] = tot;
    __syncthreads();
    // scatter into LDS sorted by bucket
#pragma unroll
    for (int i = 0; i < EPT; ++i) {
        if (cc[i] >= 0) {
            int bu = cc[i] >> 7;
            srtv[lst[bu] + pp[i]] = (rr[i] << 7) | (cc[i] & 127);
        }
    }
    __syncthreads();
    // block-major contiguous writes: packed region + offset row
    size_t base = (size_t)blockIdx.x * EPB;
    for (int p = tid; p < tot; p += PART_T) packed[base + p] = srtv[p];
    size_t ob = (size_t)blockIdx.x * (NBUCK + 1);
    for (int j = tid; j <= NBUCK; j += PART_T) off[ob + j] = lst[j];
    // block 0 extras: transposed bf16 W, zero dummy row N
    if (blockIdx.x == 0) {
        for (int i = tid; i < 4096; i += PART_T) {
            int n = i >> 6, k = i & 63;
            WT[i] = f2bf(W[k * 64 + n]);           // WT[n][k]
        }
        if (tid < 32) ((unsigned*)xw_h)[(size_t)N * 32 + tid] = 0u;
    }
}

// ---- 2. MFMA GEMM (transposed-C) + fused bucket degree + deg8 export -------
// Block g == bucket g: rows [128g, 128g+128) = 8 M-tiles, 4 waves x 2 tiles.
// mfma(A=W^T-frag, B=x-frag): thread (m,quad) holds row row0+m, cols
// t*16+quad*4.. -> 8B stores.
__global__ __launch_bounds__(256, 4)
void k_gemm(const float* __restrict__ x, const unsigned short* __restrict__ WT,
            const int* __restrict__ packed, const int* __restrict__ off,
            unsigned char* __restrict__ deg8, unsigned short* __restrict__ xw_h,
            int N, int NT, int NB1, int NBUCK) {
    __shared__ int lh[BW];
    int tid = threadIdx.x, b = blockIdx.x;
    if (tid < BW) lh[tid] = 0;
    __syncthreads();
    for (int pb = tid; pb < NB1; pb += 256) {
        const int* o = off + (size_t)pb * (NBUCK + 1) + b;
        int st = o[0], en = o[1];
        const int* pk = packed + (size_t)pb * EPB;
        for (int e = st; e < en; ++e)
            atomicAdd(&lh[pk[e] & 127], 1);
    }
    __syncthreads();
    if (tid < BW) {
        int node = b * BW + tid;
        if (node < N) deg8[node] = (unsigned char)min(lh[tid], 255);
    }
    int lane = tid & 63, wv = tid >> 6;
    int m = lane & 15, quad = lane >> 4;
    bf16x8 Bf[4][2];
#pragma unroll
    for (int t = 0; t < 4; ++t)
#pragma unroll
        for (int s = 0; s < 2; ++s)
            Bf[t][s] = *(const bf16x8*)(WT + (t * 16 + m) * 64 + s * 32 + quad * 8);
#pragma unroll
    for (int s = 0; s < 2; ++s) {
        int mt = b * 8 + s * 4 + wv;
        if (mt >= NT) continue;
        int row0 = mt * 16;
        const float* xr = x + (size_t)(row0 + m) * 64 + quad * 8;
        float4 a0 = *(const float4*)(xr);
        float4 a1 = *(const float4*)(xr + 4);
        float4 a2 = *(const float4*)(xr + 32);
        float4 a3 = *(const float4*)(xr + 36);
        bf16x8 A0, A1;
        A0[0] = (short)f2bf(a0.x); A0[1] = (short)f2bf(a0.y);
        A0[2] = (short)f2bf(a0.z); A0[3] = (short)f2bf(a0.w);
        A0[4] = (short)f2bf(a1.x); A0[5] = (short)f2bf(a1.y);
        A0[6] = (short)f2bf(a1.z); A0[7] = (short)f2bf(a1.w);
        A1[0] = (short)f2bf(a2.x); A1[1] = (short)f2bf(a2.y);
        A1[2] = (short)f2bf(a2.z); A1[3] = (short)f2bf(a2.w);
        A1[4] = (short)f2bf(a3.x); A1[5] = (short)f2bf(a3.y);
        A1[6] = (short)f2bf(a3.z); A1[7] = (short)f2bf(a3.w);
        f32x4 acc[4];
#pragma unroll
        for (int t = 0; t < 4; ++t) {
            acc[t] = (f32x4){0.f, 0.f, 0.f, 0.f};
            acc[t] = __builtin_amdgcn_mfma_f32_16x16x32_bf16(Bf[t][0], A0, acc[t], 0, 0, 0);
            acc[t] = __builtin_amdgcn_mfma_f32_16x16x32_bf16(Bf[t][1], A1, acc[t], 0, 0, 0);
        }
        float dsc = rsqrtf((float)(lh[(row0 + m) & 127] + 1));
        unsigned short* op = xw_h + (size_t)(row0 + m) * 64 + quad * 4;
#pragma unroll
        for (int t = 0; t < 4; ++t) {
            __half2 h0, h1;
            h0.x = __float2half(acc[t][0] * dsc); h0.y = __float2half(acc[t][1] * dsc);
            h1.x = __float2half(acc[t][2] * dsc); h1.y = __float2half(acc[t][3] * dsc);
            uint2 u; u.x = *(unsigned*)&h0; u.y = *(unsigned*)&h1;
            *(uint2*)(op + t * 16) = u;
        }
    }
}

// ---- 3. rank-scatter + per-lane-node gather --------------------------------
__global__ __launch_bounds__(512, 8)
void k_gather(const int* __restrict__ packed, const int* __restrict__ off,
              const unsigned char* __restrict__ deg8,
              const uint2* __restrict__ xwh, const float* __restrict__ bias,
              float4* __restrict__ out4, int N, int NB1, int NBUCK) {
    __shared__ int lh[BW], stt[BW], cur[BW];
    __shared__ int wsum[2];
    __shared__ __align__(16) int srtL[CAPL];
    int b = blockIdx.x, tid = threadIdx.x, lane = tid & 63;
    // per-node counts from deg8 (no histogram pass), padded-x4 scan
    int v = 0, vp = 0, inc = 0;
    if (tid < BW) {
        int node = b * BW + tid;
        v = (node < N) ? (int)deg8[node] : 0;
        lh[tid] = v;
        vp = (v + 3) & ~3; inc = vp;
#pragma unroll
        for (int o = 1; o < 64; o <<= 1) {
            int u = __shfl_up(inc, o);
            if (lane >= o) inc += u;
        }
        if (lane == 63) wsum[tid >> 6] = inc;
    }
    __syncthreads();
    if (tid < BW) {
        int st = inc - vp + ((tid >> 6) ? wsum[0] : 0);
        stt[tid] = st;
        cur[tid] = st;
    }
    __syncthreads();
    // one segment walk: rank-scatter rows into srtL
    for (int pb = tid; pb < NB1; pb += 512) {
        const int* o = off + (size_t)pb * (NBUCK + 1) + b;
        int st = o[0], en = o[1];
        const int* pk = packed + (size_t)pb * EPB;
        for (int e = st; e < en; ++e) {
            int p = pk[e];
            int pos = atomicAdd(&cur[p & 127], 1);
            if (pos < CAPL) srtL[pos] = p >> 7;
        }
    }
    __syncthreads();
    if (tid < BW) {            // pad each segment to x4 with dummy row N
        int e = stt[tid] + v, ep = min(stt[tid] + vp, CAPL);
        for (; e < ep; ++e) srtL[e] = N;
    }
    __syncthreads();
    int l = lane & 15;         // dim chunk: dims 4l..4l+3
    int ng = lane >> 4;        // node subgroup 0..3
    int wv = tid >> 6;         // 8 waves
    const float4 bb = ((const float4*)bias)[l];
#define ADDV(h)                                                     \
    {                                                               \
        __half2 h0 = *(__half2*)&(h).x, h1 = *(__half2*)&(h).y;     \
        float2 f0 = __half22float2(h0), f1 = __half22float2(h1);    \
        acc.x += f0.x; acc.y += f0.y; acc.z += f1.x; acc.w += f1.y; \
    }
    for (int g = 0; g < 4; ++g) {
        int nn = wv * 16 + g * 4 + ng;
        int node = b * BW + nn;
        bool active = node < N;
        float4 acc = make_float4(0.f, 0.f, 0.f, 0.f);
        int k = 0, s0 = 0;
        if (active) {
            k = lh[nn]; s0 = stt[nn];
            uint2 hs = xwh[(size_t)node * 16 + l];   // self-loop
            ADDV(hs);
        }
        int kp = (k + 3) & ~3;
        if (s0 + kp > CAPL) kp = (CAPL > s0) ? ((CAPL - s0) & ~3) : 0;
        if (kp > 0) {
            int4 rv = *(const int4*)&srtL[s0];
            int j = 0;
            while (true) {
                uint2 va = xwh[(size_t)rv.x * 16 + l];
                uint2 vb = xwh[(size_t)rv.y * 16 + l];
                uint2 vc = xwh[(size_t)rv.z * 16 + l];
                uint2 vd = xwh[(size_t)rv.w * 16 + l];
                j += 4;
                bool more = j < kp;
                if (more) rv = *(const int4*)&srtL[s0 + j];
                ADDV(va); ADDV(vb); ADDV(vc); ADDV(vd);
                if (!more) break;
            }
        }
        if (active) {
            float dn = rsqrtf((float)(k + 1));
            float4 o;
            o.x = fmaxf(fmaf(dn, acc.x, bb.x), 0.f);
            o.y = fmaxf(fmaf(dn, acc.y, bb.y), 0.f);
            o.z = fmaxf(fmaf(dn, acc.z, bb.z), 0.f);
            o.w = fmaxf(fmaf(dn, acc.w, bb.w), 0.f);
            out4[(size_t)node * 16 + l] = o;
        }
    }
#undef ADDV
}

extern "C" void kernel_launch(void* const* d_in, const int* in_sizes, int n_in,
                              void* d_out, int out_size, void* d_ws, size_t ws_size,
                              hipStream_t stream) {
    const float* x    = (const float*)d_in[0];
    const int*   ei   = (const int*)d_in[1];   // int32 (JAX demotes int64)
    const float* W    = (const float*)d_in[2];
    const float* bias = (const float*)d_in[3];
    float* out = (float*)d_out;

    const int N = in_sizes[0] / D;
    const int E = in_sizes[1] / 2;
    const int* row = ei;       // edge_index[0] = sources
    const int* col = ei + E;   // edge_index[1] = destinations

    const int NBUCK = (N + BW - 1) / BW;       // 782
    const int NB1   = (E + EPB - 1) / EPB;     // 391
    const int NT    = (N + 15) / 16;           // 6250 M-tiles

    char* ws = (char*)d_ws;
    size_t off_b = 0;
    unsigned short* xw_h = (unsigned short*)(ws + off_b);
    off_b += (size_t)(N + 1) * D * sizeof(unsigned short);         // +1 dummy row
    int* packed = (int*)(ws + off_b); off_b += (size_t)NB1 * EPB * sizeof(int);
    int* offt   = (int*)(ws + off_b); off_b += (size_t)NB1 * (NBUCK + 1) * sizeof(int);
    off_b = (off_b + 15) & ~(size_t)15;
    unsigned char* deg8 = (unsigned char*)(ws + off_b); off_b += (size_t)N;
    off_b = (off_b + 15) & ~(size_t)15;
    unsigned short* WT = (unsigned short*)(ws + off_b); off_b += 4096 * sizeof(unsigned short);

    k_part<<<NB1, PART_T, 0, stream>>>(row, col, packed, offt, WT, W, xw_h, E, NBUCK, N);
    k_gemm<<<NBUCK, 256, 0, stream>>>(x, WT, packed, offt, deg8, xw_h, N, NT, NB1, NBUCK);
    k_gather<<<NBUCK, 512, 0, stream>>>(packed, offt, deg8, (const uint2*)xw_h, bias,
                                        (float4*)out, N, NB1, NBUCK);
}